// Round 15
// baseline (119.159 us; speedup 1.0000x reference)
//
#include <hip/hip_runtime.h>
#include <hip/hip_fp16.h>

typedef __attribute__((ext_vector_type(8))) _Float16 half8;
typedef __attribute__((ext_vector_type(2))) __fp16 fp16x2;
typedef __attribute__((ext_vector_type(4))) float f32x4;
typedef unsigned short u16;
typedef unsigned int u32;

__device__ __forceinline__ u16 f2h(float f) {
  union { _Float16 h; u16 u; } cv; cv.h = (_Float16)f; return cv.u;
}

__device__ __forceinline__ u32 pkrtz(float a, float b) {
  union { fp16x2 h; u32 u; } cv;
  cv.h = __builtin_amdgcn_cvt_pkrtz(a, b);
  return cv.u;
}

__device__ __forceinline__ f32x4 mfma16h(half8 a, half8 b, f32x4 c) {
  return __builtin_amdgcn_mfma_f32_16x16x32_f16(a, b, c, 0, 0, 0);
}

__device__ __forceinline__ void gload_lds16(const void* g, void* l) {
  __builtin_amdgcn_global_load_lds(
      (const __attribute__((address_space(1))) void*)g,
      (__attribute__((address_space(3))) void*)l, 16, 0, 0);
}

__device__ __forceinline__ half8 ldh8(const char* p) {
  union { half8 h; int4 v; } r; r.v = *(const int4*)p; return r.h;
}

// 8-wide fp16 product via v_pk_mul_f16
__device__ __forceinline__ uint4 pkmul4(uint4 x, uint4 y) {
  union U { uint4 v; __half2 h[4]; };
  U X, Y, E; X.v = x; Y.v = y;
  #pragma unroll
  for (int i = 0; i < 4; i++) E.h[i] = __hmul2(X.h[i], Y.h[i]);
  return E.v;
}
__device__ __forceinline__ half8 as_h8(uint4 v) {
  union { uint4 v; half8 h; } r; r.v = v; return r.h;
}

// ---- one row of weight-norm (fp16 out), wave-cooperative ----
__device__ __forceinline__ void wn_row(const float* __restrict__ v,
                                       const float* __restrict__ g,
                                       int K, int Nreal, u16* __restrict__ outW,
                                       int row, int l) {
  if (row >= Nreal) {
    for (int k = l; k < K; k += 64) outW[row * K + k] = 0;
    return;
  }
  const float* vr = v + (size_t)row * K;
  float ss = 0.f;
  for (int k = l * 4; k < K; k += 256) {
    f32x4 x = *(const f32x4*)(vr + k);
    ss += x.x * x.x + x.y * x.y + x.z * x.z + x.w * x.w;
  }
  #pragma unroll
  for (int m = 32; m >= 1; m >>= 1) ss += __shfl_xor(ss, m, 64);
  const float scale = g[row] / sqrtf(ss);
  for (int k = l; k < K; k += 64) outW[row * K + k] = f2h(vr[k] * scale);
}

// ---- merged prep: weight-norm (blocks 0..323) + pos scatter / ij_tab (324..959) ----
// W1f layout: [kc(16)][row(256)][32] fp16, PLAIN (read from global in edge).
__global__ __launch_bounds__(256) void wn_scatter(
    const float* __restrict__ v_obj, const float* __restrict__ g_obj,
    const float* __restrict__ v_q,   const float* __restrict__ g_q,
    const float* __restrict__ v_l1,  const float* __restrict__ g_l1,
    const float* __restrict__ v_l2,  const float* __restrict__ g_l2,
    u16* __restrict__ Wobjh, u16* __restrict__ Wqh,
    u16* __restrict__ W1f,   u16* __restrict__ W2p,
    const int* __restrict__ indexes, int* __restrict__ posPair,
    int* __restrict__ ij_tab) {
  const int b = blockIdx.x;
  const int sub = threadIdx.x >> 6, l = threadIdx.x & 63;
  if (b < 128) {
    wn_row(v_obj, g_obj, 2048, 512, Wobjh, b * 4 + sub, l);
  } else if (b < 256) {
    wn_row(v_q, g_q, 1024, 512, Wqh, (b - 128) * 4 + sub, l);
  } else if (b < 320) {
    const int row = (b - 256) * 4 + sub;
    const float* vr = v_l1 + (size_t)row * 512;
    float ss = 0.f;
    for (int k = l * 4; k < 512; k += 256) {
      f32x4 x = *(const f32x4*)(vr + k);
      ss += x.x * x.x + x.y * x.y + x.z * x.z + x.w * x.w;
    }
    #pragma unroll
    for (int m = 32; m >= 1; m >>= 1) ss += __shfl_xor(ss, m, 64);
    const float scale = g_l1[row] / sqrtf(ss);
    for (int c = l; c < 512; c += 64)
      W1f[(c >> 5) * 8192 + row * 32 + (c & 31)] = f2h(vr[c] * scale);
  } else if (b < 324) {
    wn_row(v_l2, g_l2, 256, 8, W2p, (b - 320) * 4 + sub, l);
  } else {
    const int m = (b - 324) * 256 + threadIdx.x;
    if (m < 161280) {
      const int idx = indexes[m];
      const int bi = idx / 1296;
      const int rem = idx - bi * 1296;
      const int i = rem / 36, j = rem - i * 36;
      const int i2 = (i < j) ? i : j, j2 = (i < j) ? j : i;
      const int p = i2 * (71 - i2) / 2 + (j2 - i2 - 1);
      posPair[(bi * 640 + p) * 2 + ((i < j) ? 0 : 1)] = m;
    } else {
      const int u = m - 161280;
      if (u < 1296) {
        const int i = u / 36, j = u - i * 36;
        if (i < j) ij_tab[i * (71 - i) / 2 + (j - i - 1)] = u;
      } else if (u < 1306) {
        ij_tab[630 + (u - 1296)] = 35 * 36 + 35;
      }
    }
  }
}

// ---- bulk fp32 -> fp16 convert: node (9437184) then q (131072), one launch ----
__global__ void cvt_all(const float* __restrict__ node, u16* __restrict__ node_h,
                        const float* __restrict__ qf, u16* __restrict__ q_h) {
  const int i = (blockIdx.x * 256 + threadIdx.x) * 8;
  const float* in; u16* out; int off;
  if (i < 9437184) { in = node; out = node_h; off = i; }
  else             { in = qf;   out = q_h;    off = i - 9437184; }
  f32x4 a = *(const f32x4*)(in + off);
  f32x4 b = *(const f32x4*)(in + off + 4);
  uint4 r;
  r.x = pkrtz(a.x, a.y); r.y = pkrtz(a.z, a.w);
  r.z = pkrtz(b.x, b.y); r.w = pkrtz(b.z, b.w);
  *(uint4*)(out + off) = r;
}

// ================= LDS-staged stage-1 GEMM, fp16, 128x64 tile (R12 proven) =================
template <int MODE>
__global__ __launch_bounds__(256, 3) void gemm_lds(
    const u16* __restrict__ Ab, const u16* __restrict__ Wb,
    int K, int nstep, const float* __restrict__ bias,
    float* __restrict__ fout, u16* __restrict__ o_a2) {
  __shared__ char smem[2][24576];
  const int t = threadIdx.x, l = t & 63, w = t >> 6;
  const int lr = l & 15, lg = l >> 4;
  const int wm = w & 1, wn2 = w >> 1;
  const int bm = blockIdx.x * 128, bn = blockIdx.y * 64;
  const int kbase = (MODE == 0) ? blockIdx.z * 128 : 0;
  const int ldb = K * 2;

  const char* Abase = (const char*)(Ab + (size_t)bm * K + kbase);
  const char* Bbase = (const char*)(Wb + (size_t)bn * K + kbase);

  auto stage = [&](int buf, int ks) {
    const char* asrc = Abase + ks * 128;
    const char* bsrc = Bbase + ks * 128;
    #pragma unroll
    for (int it = 0; it < 4; it++) {
      const int c = it * 256 + w * 64 + l;
      const int row = c >> 3;
      const int cb = ((c & 7) * 16) ^ ((row & 7) << 4);
      gload_lds16(asrc + (size_t)row * ldb + cb, &smem[buf][(it * 256 + w * 64) * 16]);
    }
    #pragma unroll
    for (int it = 0; it < 2; it++) {
      const int c = it * 256 + w * 64 + l;
      const int row = c >> 3;
      const int cb = ((c & 7) * 16) ^ ((row & 7) << 4);
      gload_lds16(bsrc + (size_t)row * ldb + cb,
                  &smem[buf][16384 + (it * 256 + w * 64) * 16]);
    }
  };

  stage(0, 0);
  asm volatile("s_waitcnt vmcnt(0)" ::: "memory");
  __builtin_amdgcn_s_barrier();

  f32x4 acc[4][2] = {};
  for (int ks = 0; ks < nstep; ks++) {
    const int cur = ks & 1;
    if (ks + 1 < nstep) stage(cur ^ 1, ks + 1);
    const char* As = smem[cur];
    const char* Bs = smem[cur] + 16384;
    #pragma unroll
    for (int kk = 0; kk < 2; kk++) {
      half8 af[4], bf[2];
      #pragma unroll
      for (int m = 0; m < 4; m++) {
        const int r = wm * 64 + m * 16 + lr;
        af[m] = ldh8(As + r * 128 + ((kk * 64 + lg * 16) ^ ((lr & 7) << 4)));
      }
      #pragma unroll
      for (int n = 0; n < 2; n++) {
        const int r = wn2 * 32 + n * 16 + lr;
        bf[n] = ldh8(Bs + r * 128 + ((kk * 64 + lg * 16) ^ ((lr & 7) << 4)));
      }
      #pragma unroll
      for (int m = 0; m < 4; m++)
        #pragma unroll
        for (int n = 0; n < 2; n++)
          acc[m][n] = mfma16h(af[m], bf[n], acc[m][n]);
    }
    asm volatile("s_waitcnt vmcnt(0)" ::: "memory");
    __builtin_amdgcn_s_barrier();
  }

  #pragma unroll
  for (int n = 0; n < 2; n++) {
    const int c = bn + wn2 * 32 + n * 16 + lr;
    const float bv = (MODE == 1) ? bias[c] : 0.f;
    #pragma unroll
    for (int m = 0; m < 4; m++) {
      #pragma unroll
      for (int q = 0; q < 4; q++) {
        const int r = bm + wm * 64 + m * 16 + lg * 4 + q;
        const float val = acc[m][n][q];
        if (MODE == 0) {
          fout[((size_t)blockIdx.z * 128 + r) * 512 + c] = val;
        } else {
          o_a2[(size_t)r * 512 + c] = f2h(val + bv);
        }
      }
    }
  }
}

// ---- split-K reduce for qp -> fp16 ----
__global__ void qp_reduce(const float* __restrict__ part, const float* __restrict__ bq,
                          u16* __restrict__ qp_h) {
  const int i = (blockIdx.x * 256 + threadIdx.x) * 4;
  f32x4 s = *(const f32x4*)(part + i);
  #pragma unroll
  for (int k = 1; k < 8; k++) {
    f32x4 v = *(const f32x4*)(part + (size_t)k * 65536 + i);
    s.x += v.x; s.y += v.y; s.z += v.z; s.w += v.w;
  }
  const int c = i & 511;
  uint2 r;
  r.x = pkrtz(s.x + bq[c], s.y + bq[c + 1]);
  r.y = pkrtz(s.z + bq[c + 2], s.w + bq[c + 3]);
  *(uint2*)(qp_h + i) = r;
}

// ================= fused edge kernel v12: reg-double-buffered global W1 =================
// W1 B-fragments live in REGISTERS (bfA/bfB, 2-phase unrolled kc), loaded
// straight from global (per-wave 1KB coalesced, L2-hot) one full MFMA phase
// ahead -> latency covered. No W1 LDS, no K-loop barriers.
// LDS = 67,584 B: nf/qp tables (38,464) in front, and the epilogue h-tile
// [128][528B] = 67,584 B aliases the whole region (2 blocks/CU).
#define OFF_QP 37440
#define EDGE_SMEM 67584

__global__ __launch_bounds__(256, 2) void edge_v12(
    const u16* __restrict__ NFg, const u16* __restrict__ QPg,
    const u16* __restrict__ W1f, const float* __restrict__ b1,
    const u16* __restrict__ W2p, const float* __restrict__ b2,
    const int* __restrict__ posPair, const int* __restrict__ ij_tab,
    float* __restrict__ out) {
  extern __shared__ char smem[];
  const int t = threadIdx.x, l = t & 63, w = t >> 6;
  const int lr = l & 15, lg = l >> 4;
  const int wm = w & 1, wn = w >> 1;
  const int bi = blockIdx.y;
  const int mb = blockIdx.x * 128;

  // ---- prologue: nf rows 0..35 + qp row into LDS ----
  #pragma unroll
  for (int it = 0; it < 10; it++) {
    const int row = it * 4 + w;            // wave-uniform
    if (row < 36) {
      gload_lds16(NFg + (size_t)(bi * 36 + row) * 512 + l * 8, smem + row * 1040);
    } else if (row == 36) {
      gload_lds16(QPg + (size_t)bi * 512 + l * 8, smem + OFF_QP);
    }
  }

  // ---- per-thread A-gen offsets for the 4 m-tiles (pair -> i,j via ij_tab) ----
  int xoff[4], yoff[4];
  #pragma unroll
  for (int m = 0; m < 4; m++) {
    const int p = mb + wm * 64 + m * 16 + lr;
    const int pij = ij_tab[p];
    const int ii = pij / 36;
    const int jj = pij - ii * 36;
    xoff[m] = ii * 1040 + lg * 16;
    yoff[m] = jj * 1040 + lg * 16;
  }
  const int qoff = OFF_QP + lg * 16;

  // per-lane W1 global base: row = wn*128 + lr, 16B at lg*8; +n*1024B/n-tile, +kc*16384B
  const char* wb = (const char*)(W1f + (size_t)(wn * 128 + lr) * 32 + lg * 8);

  asm volatile("s_waitcnt vmcnt(0)" ::: "memory");
  __builtin_amdgcn_s_barrier();           // tables ready

  f32x4 acc[4][8] = {};
  half8 bfA[8], bfB[8];
  #pragma unroll
  for (int n = 0; n < 8; n++) bfA[n] = ldh8(wb + n * 1024);   // kc=0

  #pragma unroll
  for (int kc2 = 0; kc2 < 16; kc2 += 2) {
    // prefetch kc2+1 into bfB
    #pragma unroll
    for (int n = 0; n < 8; n++)
      bfB[n] = ldh8(wb + (size_t)(kc2 + 1) * 16384 + n * 1024);
    // MFMA phase kc2 with bfA
    {
      const int kb = kc2 * 64;
      const uint4 qv = *(const uint4*)(smem + qoff + kb);
      #pragma unroll
      for (int m = 0; m < 4; m++) {
        uint4 x = *(const uint4*)(smem + xoff[m] + kb);
        uint4 y = *(const uint4*)(smem + yoff[m] + kb);
        half8 af = as_h8(pkmul4(pkmul4(x, y), qv));
        #pragma unroll
        for (int n = 0; n < 8; n++)
          acc[m][n] = mfma16h(af, bfA[n], acc[m][n]);
      }
    }
    // prefetch kc2+2 into bfA
    if (kc2 + 2 < 16) {
      #pragma unroll
      for (int n = 0; n < 8; n++)
        bfA[n] = ldh8(wb + (size_t)(kc2 + 2) * 16384 + n * 1024);
    }
    // MFMA phase kc2+1 with bfB
    {
      const int kb = (kc2 + 1) * 64;
      const uint4 qv = *(const uint4*)(smem + qoff + kb);
      #pragma unroll
      for (int m = 0; m < 4; m++) {
        uint4 x = *(const uint4*)(smem + xoff[m] + kb);
        uint4 y = *(const uint4*)(smem + yoff[m] + kb);
        half8 af = as_h8(pkmul4(pkmul4(x, y), qv));
        #pragma unroll
        for (int n = 0; n < 8; n++)
          acc[m][n] = mfma16h(af, bfB[n], acc[m][n]);
      }
    }
  }

  // ---- epilogue: bias+relu -> fp16 h tile [128][528B] (aliases nf/qp) ----
  __syncthreads();                         // all waves done reading tables
  #pragma unroll
  for (int m = 0; m < 4; m++) {
    #pragma unroll
    for (int n = 0; n < 8; n++) {
      const int c = wn * 128 + n * 16 + lr;
      const float bv = b1[c];
      #pragma unroll
      for (int qq = 0; qq < 2; qq++) {
        const float v0 = fmaxf(acc[m][n][2 * qq] + bv, 0.f);
        const float v1 = fmaxf(acc[m][n][2 * qq + 1] + bv, 0.f);
        const u32 pk = pkrtz(v0, v1);
        const int r = wm * 64 + m * 16 + lg * 4 + 2 * qq;
        *(u16*)(smem + r * 528 + c * 2) = (u16)pk;
        *(u16*)(smem + (r + 1) * 528 + c * 2) = (u16)(pk >> 16);
      }
    }
  }
  __syncthreads();

  // ---- GEMM2: out = h @ W2p^T + b2, K=256; dual scatter to both orderings ----
  half8 w2f[8];
  #pragma unroll
  for (int kk = 0; kk < 8; kk++)
    w2f[kk] = ldh8((const char*)(W2p + lr * 256 + kk * 32 + lg * 8));

  #pragma unroll
  for (int tt = 0; tt < 2; tt++) {
    const int tile = tt * 4 + w;
    f32x4 a2c = {0.f, 0.f, 0.f, 0.f};
    #pragma unroll
    for (int kk = 0; kk < 8; kk++) {
      half8 af = ldh8(smem + (tile * 16 + lr) * 528 + kk * 64 + lg * 16);
      a2c = mfma16h(af, w2f[kk], a2c);
    }
    if (lr < 8) {
      const float b2v = b2[lr];
      #pragma unroll
      for (int q = 0; q < 4; q++) {
        const int p = mb + tile * 16 + lg * 4 + q;
        const int m0 = posPair[(bi * 640 + p) * 2];
        const int m1 = posPair[(bi * 640 + p) * 2 + 1];
        const float val = a2c[q] + b2v;
        if (m0 >= 0) out[(size_t)m0 * 8 + lr] = val;
        if (m1 >= 0) out[(size_t)m1 * 8 + lr] = val;
      }
    }
  }
}

extern "C" void kernel_launch(void* const* d_in, const int* in_sizes, int n_in,
                              void* d_out, int out_size, void* d_ws, size_t ws_size,
                              hipStream_t stream) {
  const float* node_feats = (const float*)d_in[0];
  const float* q_feats    = (const float*)d_in[1];
  const int*   indexes    = (const int*)d_in[2];
  const float* v_obj = (const float*)d_in[3];
  const float* g_obj = (const float*)d_in[4];
  const float* b_obj = (const float*)d_in[5];
  const float* v_q   = (const float*)d_in[6];
  const float* g_q   = (const float*)d_in[7];
  const float* b_q   = (const float*)d_in[8];
  const float* v_l1  = (const float*)d_in[9];
  const float* g_l1  = (const float*)d_in[10];
  const float* b_l1  = (const float*)d_in[11];
  const float* v_l2  = (const float*)d_in[12];
  const float* g_l2  = (const float*)d_in[13];
  const float* b_l2  = (const float*)d_in[14];
  float* out = (float*)d_out;

  char* ws = (char*)d_ws;
  u16*   node_h  = (u16*)(ws + 0);               // 18,874,368
  u16*   q_h     = (u16*)(ws + 18874368);        //    262,144
  u16*   Wobjh   = (u16*)(ws + 19136512);        //  2,097,152
  u16*   Wqh     = (u16*)(ws + 21233664);        //  1,048,576
  u16*   W1f     = (u16*)(ws + 22282240);        //    262,144 (16x256x32 fp16, plain)
  u16*   W2p     = (u16*)(ws + 22544384);        //      8,192
  u16*   qp_h    = (u16*)(ws + 22552576);        //    131,072 (128x512 fp16)
  u16*   A2h     = (u16*)(ws + 22683648);        //  4,718,592 (nf fp16)
  int*   posPair = (int*)(ws + 27402240);        //    655,360 (128x640x2)
  int*   ij_tab  = (int*)(ws + 28057600);        //      2,560 (640)
  float* part    = (float*)(ws + 28060160);      //  2,097,152

  hipMemsetAsync(posPair, 0xFF, 655360, stream);

  wn_scatter<<<dim3(960), dim3(256), 0, stream>>>(v_obj, g_obj, v_q, g_q, v_l1, g_l1,
                                                  v_l2, g_l2, Wobjh, Wqh, W1f, W2p,
                                                  indexes, posPair, ij_tab);

  cvt_all<<<dim3(4672), dim3(256), 0, stream>>>(node_feats, node_h, q_feats, q_h);

  gemm_lds<0><<<dim3(1, 8, 8), dim3(256), 0, stream>>>(q_h, Wqh, 1024, 2, nullptr,
                                                       part, nullptr);
  qp_reduce<<<dim3(64), dim3(256), 0, stream>>>(part, b_q, qp_h);

  gemm_lds<1><<<dim3(36, 8), dim3(256), 0, stream>>>(node_h, Wobjh, 2048, 32, b_obj,
                                                     nullptr, A2h);

  edge_v12<<<dim3(5, 128), dim3(256), EDGE_SMEM, stream>>>(A2h, qp_h, W1f, b_l1,
                                                           W2p, b_l2, posPair, ij_tab, out);
}

// Round 16
// 101.964 us; speedup vs baseline: 1.1686x; 1.1686x over previous
//
#include <hip/hip_runtime.h>
#include <hip/hip_fp16.h>

typedef __attribute__((ext_vector_type(8))) _Float16 half8;
typedef __attribute__((ext_vector_type(2))) __fp16 fp16x2;
typedef __attribute__((ext_vector_type(4))) float f32x4;
typedef unsigned short u16;
typedef unsigned int u32;

__device__ __forceinline__ u16 f2h(float f) {
  union { _Float16 h; u16 u; } cv; cv.h = (_Float16)f; return cv.u;
}

__device__ __forceinline__ u32 pkrtz(float a, float b) {
  union { fp16x2 h; u32 u; } cv;
  cv.h = __builtin_amdgcn_cvt_pkrtz(a, b);
  return cv.u;
}

__device__ __forceinline__ f32x4 mfma16h(half8 a, half8 b, f32x4 c) {
  return __builtin_amdgcn_mfma_f32_16x16x32_f16(a, b, c, 0, 0, 0);
}

__device__ __forceinline__ void gload_lds16(const void* g, void* l) {
  __builtin_amdgcn_global_load_lds(
      (const __attribute__((address_space(1))) void*)g,
      (__attribute__((address_space(3))) void*)l, 16, 0, 0);
}

__device__ __forceinline__ half8 ldh8(const char* p) {
  union { half8 h; int4 v; } r; r.v = *(const int4*)p; return r.h;
}

// 8-wide fp16 product via v_pk_mul_f16
__device__ __forceinline__ uint4 pkmul4(uint4 x, uint4 y) {
  union U { uint4 v; __half2 h[4]; };
  U X, Y, E; X.v = x; Y.v = y;
  #pragma unroll
  for (int i = 0; i < 4; i++) E.h[i] = __hmul2(X.h[i], Y.h[i]);
  return E.v;
}
__device__ __forceinline__ half8 as_h8(uint4 v) {
  union { uint4 v; half8 h; } r; r.v = v; return r.h;
}

// ---- one row of weight-norm (fp16 out), wave-cooperative ----
__device__ __forceinline__ void wn_row(const float* __restrict__ v,
                                       const float* __restrict__ g,
                                       int K, int Nreal, u16* __restrict__ outW,
                                       int row, int l) {
  if (row >= Nreal) {
    for (int k = l; k < K; k += 64) outW[row * K + k] = 0;
    return;
  }
  const float* vr = v + (size_t)row * K;
  float ss = 0.f;
  for (int k = l * 4; k < K; k += 256) {
    f32x4 x = *(const f32x4*)(vr + k);
    ss += x.x * x.x + x.y * x.y + x.z * x.z + x.w * x.w;
  }
  #pragma unroll
  for (int m = 32; m >= 1; m >>= 1) ss += __shfl_xor(ss, m, 64);
  const float scale = g[row] / sqrtf(ss);
  for (int k = l; k < K; k += 64) outW[row * K + k] = f2h(vr[k] * scale);
}

// ---- merged prep: weight-norm (blocks 0..323) + pos scatter / ij_tab (324..959) ----
// W1f layout: [kc(16)][row(256)][32] fp16, quad q stored at q ^ ((row>>1)&3)
// (pre-swizzled for conflict-free LDS reads in edge_v11).
__global__ __launch_bounds__(256) void wn_scatter(
    const float* __restrict__ v_obj, const float* __restrict__ g_obj,
    const float* __restrict__ v_q,   const float* __restrict__ g_q,
    const float* __restrict__ v_l1,  const float* __restrict__ g_l1,
    const float* __restrict__ v_l2,  const float* __restrict__ g_l2,
    u16* __restrict__ Wobjh, u16* __restrict__ Wqh,
    u16* __restrict__ W1f,   u16* __restrict__ W2p,
    const int* __restrict__ indexes, int* __restrict__ posPair,
    int* __restrict__ ij_tab) {
  const int b = blockIdx.x;
  const int sub = threadIdx.x >> 6, l = threadIdx.x & 63;
  if (b < 128) {
    wn_row(v_obj, g_obj, 2048, 512, Wobjh, b * 4 + sub, l);
  } else if (b < 256) {
    wn_row(v_q, g_q, 1024, 512, Wqh, (b - 128) * 4 + sub, l);
  } else if (b < 320) {
    const int row = (b - 256) * 4 + sub;
    const float* vr = v_l1 + (size_t)row * 512;
    float ss = 0.f;
    for (int k = l * 4; k < 512; k += 256) {
      f32x4 x = *(const f32x4*)(vr + k);
      ss += x.x * x.x + x.y * x.y + x.z * x.z + x.w * x.w;
    }
    #pragma unroll
    for (int m = 32; m >= 1; m >>= 1) ss += __shfl_xor(ss, m, 64);
    const float scale = g_l1[row] / sqrtf(ss);
    const int swz = (row >> 1) & 3;
    for (int c = l; c < 512; c += 64) {
      const int kc = c >> 5, col = c & 31, q = col >> 3, e = col & 7;
      W1f[kc * 8192 + row * 32 + ((q ^ swz) << 3) + e] = f2h(vr[c] * scale);
    }
  } else if (b < 324) {
    wn_row(v_l2, g_l2, 256, 8, W2p, (b - 320) * 4 + sub, l);
  } else {
    const int m = (b - 324) * 256 + threadIdx.x;
    if (m < 161280) {
      const int idx = indexes[m];
      const int bi = idx / 1296;
      const int rem = idx - bi * 1296;
      const int i = rem / 36, j = rem - i * 36;
      const int i2 = (i < j) ? i : j, j2 = (i < j) ? j : i;
      const int p = i2 * (71 - i2) / 2 + (j2 - i2 - 1);
      posPair[(bi * 640 + p) * 2 + ((i < j) ? 0 : 1)] = m;
    } else {
      const int u = m - 161280;
      if (u < 1296) {
        const int i = u / 36, j = u - i * 36;
        if (i < j) ij_tab[i * (71 - i) / 2 + (j - i - 1)] = u;
      } else if (u < 1306) {
        ij_tab[630 + (u - 1296)] = 35 * 36 + 35;
      }
    }
  }
}

// ================= stage-1 GEMM: fused fp32-A conversion + counted-vmcnt pipeline ====
// 128x64 tile, BK=64, 4 waves (2M x 2N of 64x32). A: fp32 global -> regs ->
// pkrtz -> swizzled ds_write (geometry refcheck'd in R13). B: fp16 global via
// gload_lds (inverse-swizzled src). Per step: issue next A(8 loads)+B(2 DMA);
// vmcnt(10) [B(ks) landed, next loads stay in flight]; barrier; compute;
// vmcnt(2) [A regs ready]; ds_write; lgkmcnt(0); barrier. NO vmcnt(0) in
// steady state -> load latency hides under compute even at 1 block/CU.
// MODE 0: fp32 split-K partials (kbase = z*128). MODE 1: o_a2 = f16(C+bias).
template <int MODE>
__global__ __launch_bounds__(256, 3) void gemm_f2(
    const float* __restrict__ Af, const u16* __restrict__ Wb,
    int K, int nstep, const float* __restrict__ bias,
    float* __restrict__ fout, u16* __restrict__ o_a2) {
  __shared__ char smem[2][24576];   // [buf][ A 128x128B | B 64x128B ]
  const int t = threadIdx.x, l = t & 63, w = t >> 6;
  const int lr = l & 15, lg = l >> 4;
  const int wm = w & 1, wn2 = w >> 1;
  const int bm = blockIdx.x * 128, bn = blockIdx.y * 64;
  const int kbase = (MODE == 0) ? blockIdx.z * 128 : 0;
  const int ldb = K * 2;

  // A-chunk geometry: 1024 16B-chunks per step; thread t covers c = it*256+t.
  int arow[4], acb[4];
  #pragma unroll
  for (int it = 0; it < 4; it++) {
    const int c = it * 256 + t;
    arow[it] = c >> 3;
    acb[it] = ((c & 7) * 16) ^ ((arow[it] & 7) << 4);
  }

  auto issueA = [&](int ks, f32x4* areg) {
    #pragma unroll
    for (int it = 0; it < 4; it++) {
      const float* as = Af + (size_t)(bm + arow[it]) * K + kbase + ks * 64 + (it * 256 + t & 7) * 8;
      // note: (it*256+t)&7 == t&7 when 256%8==0; use precomputed form below
      areg[it * 2]     = *(const f32x4*)(as);
      areg[it * 2 + 1] = *(const f32x4*)(as + 4);
    }
  };
  auto issueB = [&](int buf, int ks) {
    #pragma unroll
    for (int it = 0; it < 2; it++) {
      const int c = it * 256 + w * 64 + l;
      const int row = c >> 3;
      const int cb = ((c & 7) * 16) ^ ((row & 7) << 4);
      gload_lds16((const char*)(Wb + (size_t)(bn + row) * K + kbase + ks * 64) + cb,
                  &smem[buf][16384 + (it * 256 + w * 64) * 16]);
    }
  };
  auto writeA = [&](int buf, const f32x4* areg) {
    #pragma unroll
    for (int it = 0; it < 4; it++) {
      uint4 r;
      r.x = pkrtz(areg[it * 2].x, areg[it * 2].y);
      r.y = pkrtz(areg[it * 2].z, areg[it * 2].w);
      r.z = pkrtz(areg[it * 2 + 1].x, areg[it * 2 + 1].y);
      r.w = pkrtz(areg[it * 2 + 1].z, areg[it * 2 + 1].w);
      *(uint4*)&smem[buf][arow[it] * 128 + acb[it]] = r;
    }
  };

  // prologue: A(0)->regs, B(0)->buf0; vmcnt(2) = A done; write A(0)
  f32x4 areg[8];
  issueA(0, areg);
  issueB(0, 0);
  asm volatile("s_waitcnt vmcnt(2)" ::: "memory");
  writeA(0, areg);
  asm volatile("s_waitcnt lgkmcnt(0)" ::: "memory");
  __builtin_amdgcn_s_barrier();   // A(0) visible; B(0) still in flight (2)

  f32x4 acc[4][2] = {};
  int cur = 0;
  for (int ks = 0; ks < nstep; ks++) {
    const int nxt = cur ^ 1;
    const bool more = (ks + 1 < nstep);
    if (more) {
      issueA(ks + 1, areg);     // 8 loads
      issueB(nxt, ks + 1);      // 2 DMA
      asm volatile("s_waitcnt vmcnt(10)" ::: "memory");  // B(ks) landed
    } else {
      asm volatile("s_waitcnt vmcnt(0)" ::: "memory");
    }
    __builtin_amdgcn_s_barrier();   // all waves' stage(ks) complete

    const char* As = smem[cur];
    const char* Bs = smem[cur] + 16384;
    #pragma unroll
    for (int kk = 0; kk < 2; kk++) {
      const int kswz = (kk * 64 + lg * 16) ^ ((lr & 7) << 4);
      half8 af[4], bf[2];
      #pragma unroll
      for (int m = 0; m < 4; m++)
        af[m] = ldh8(As + (wm * 64 + m * 16 + lr) * 128 + kswz);
      #pragma unroll
      for (int n = 0; n < 2; n++)
        bf[n] = ldh8(Bs + (wn2 * 32 + n * 16 + lr) * 128 + kswz);
      #pragma unroll
      for (int m = 0; m < 4; m++)
        #pragma unroll
        for (int n = 0; n < 2; n++)
          acc[m][n] = mfma16h(af[m], bf[n], acc[m][n]);
    }

    if (more) {
      asm volatile("s_waitcnt vmcnt(2)" ::: "memory");   // A(ks+1) regs ready
      writeA(nxt, areg);
    }
    asm volatile("s_waitcnt lgkmcnt(0)" ::: "memory");
    __builtin_amdgcn_s_barrier();   // writes visible; reads of buf[cur] done
    cur = nxt;
  }

  #pragma unroll
  for (int n = 0; n < 2; n++) {
    const int c = bn + wn2 * 32 + n * 16 + lr;
    const float bv = (MODE == 1) ? bias[c] : 0.f;
    #pragma unroll
    for (int m = 0; m < 4; m++) {
      #pragma unroll
      for (int q = 0; q < 4; q++) {
        const int r = bm + wm * 64 + m * 16 + lg * 4 + q;
        const float val = acc[m][n][q];
        if (MODE == 0) {
          fout[((size_t)blockIdx.z * 128 + r) * 512 + c] = val;
        } else {
          o_a2[(size_t)r * 512 + c] = f2h(val + bv);
        }
      }
    }
  }
}

// ---- split-K reduce for qp -> fp16 ----
__global__ void qp_reduce(const float* __restrict__ part, const float* __restrict__ bq,
                          u16* __restrict__ qp_h) {
  const int i = (blockIdx.x * 256 + threadIdx.x) * 4;
  f32x4 s = *(const f32x4*)(part + i);
  #pragma unroll
  for (int k = 1; k < 8; k++) {
    f32x4 v = *(const f32x4*)(part + (size_t)k * 65536 + i);
    s.x += v.x; s.y += v.y; s.z += v.z; s.w += v.w;
  }
  const int c = i & 511;
  uint2 r;
  r.x = pkrtz(s.x + bq[c], s.y + bq[c + 1]);
  r.y = pkrtz(s.z + bq[c + 2], s.w + bq[c + 3]);
  *(uint2*)(qp_h + i) = r;
}

// ================= fused edge kernel v11 (R12-proven, restored verbatim) =================
#define OFF_QP 37440
#define OFF_W1 38464
#define EDGE_SMEM 71232

__global__ __launch_bounds__(256, 2) void edge_v11(
    const u16* __restrict__ NFg, const u16* __restrict__ QPg,
    const u16* __restrict__ W1f, const float* __restrict__ b1,
    const u16* __restrict__ W2p, const float* __restrict__ b2,
    const int* __restrict__ posPair, const int* __restrict__ ij_tab,
    float* __restrict__ out) {
  extern __shared__ char smem[];
  const int t = threadIdx.x, l = t & 63, w = t >> 6;
  const int lr = l & 15, lg = l >> 4;
  const int wm = w & 1, wn = w >> 1;
  const int bi = blockIdx.y;
  const int mb = blockIdx.x * 128;

  #pragma unroll
  for (int it = 0; it < 10; it++) {
    const int row = it * 4 + w;
    if (row < 36) {
      gload_lds16(NFg + (size_t)(bi * 36 + row) * 512 + l * 8, smem + row * 1040);
    } else if (row == 36) {
      gload_lds16(QPg + (size_t)bi * 512 + l * 8, smem + OFF_QP);
    }
  }
  #pragma unroll
  for (int it = 0; it < 4; it++) {
    gload_lds16(W1f + (size_t)(it * 256 + w * 64 + l) * 8,
                smem + OFF_W1 + (it * 256 + w * 64) * 16);
  }

  int xoff[4], yoff[4];
  #pragma unroll
  for (int m = 0; m < 4; m++) {
    const int p = mb + wm * 64 + m * 16 + lr;
    const int pij = ij_tab[p];
    const int ii = pij / 36;
    const int jj = pij - ii * 36;
    xoff[m] = ii * 1040 + lg * 16;
    yoff[m] = jj * 1040 + lg * 16;
  }
  const int qoff = OFF_QP + lg * 16;
  const int bswz = ((lr >> 1) & 3) << 4;

  asm volatile("s_waitcnt vmcnt(0)" ::: "memory");
  __builtin_amdgcn_s_barrier();

  f32x4 acc[4][8] = {};
  int cur = 0;

  for (int kc = 0; kc < 16; kc++) {
    const int nxt = cur ^ 1;
    if (kc < 15) {
      #pragma unroll
      for (int it = 0; it < 4; it++) {
        gload_lds16(W1f + (size_t)(kc + 1) * 8192 + (size_t)(it * 256 + w * 64 + l) * 8,
                    smem + OFF_W1 + nxt * 16384 + (it * 256 + w * 64) * 16);
      }
    }
    {
      const char* w1c = smem + OFF_W1 + cur * 16384;
      const int kb = kc * 64;
      const uint4 qv = *(const uint4*)(smem + qoff + kb);
      half8 bf[8];
      #pragma unroll
      for (int n = 0; n < 8; n++)
        bf[n] = ldh8(w1c + (wn * 128 + n * 16 + lr) * 64 + ((lg * 16) ^ bswz));
      #pragma unroll
      for (int m = 0; m < 4; m++) {
        uint4 x = *(const uint4*)(smem + xoff[m] + kb);
        uint4 y = *(const uint4*)(smem + yoff[m] + kb);
        half8 af = as_h8(pkmul4(pkmul4(x, y), qv));
        #pragma unroll
        for (int n = 0; n < 8; n++)
          acc[m][n] = mfma16h(af, bf[n], acc[m][n]);
      }
    }
    asm volatile("s_waitcnt vmcnt(0)" ::: "memory");
    __builtin_amdgcn_s_barrier();
    cur = nxt;
  }

  #pragma unroll
  for (int m = 0; m < 4; m++) {
    #pragma unroll
    for (int n = 0; n < 8; n++) {
      const int c = wn * 128 + n * 16 + lr;
      const float bv = b1[c];
      #pragma unroll
      for (int qq = 0; qq < 2; qq++) {
        const float v0 = fmaxf(acc[m][n][2 * qq] + bv, 0.f);
        const float v1 = fmaxf(acc[m][n][2 * qq + 1] + bv, 0.f);
        const u32 pk = pkrtz(v0, v1);
        const int r = wm * 64 + m * 16 + lg * 4 + 2 * qq;
        *(u16*)(smem + r * 528 + c * 2) = (u16)pk;
        *(u16*)(smem + (r + 1) * 528 + c * 2) = (u16)(pk >> 16);
      }
    }
  }
  __syncthreads();

  half8 w2f[8];
  #pragma unroll
  for (int kk = 0; kk < 8; kk++)
    w2f[kk] = ldh8((const char*)(W2p + lr * 256 + kk * 32 + lg * 8));

  #pragma unroll
  for (int tt = 0; tt < 2; tt++) {
    const int tile = tt * 4 + w;
    f32x4 a2c = {0.f, 0.f, 0.f, 0.f};
    #pragma unroll
    for (int kk = 0; kk < 8; kk++) {
      half8 af = ldh8(smem + (tile * 16 + lr) * 528 + kk * 64 + lg * 16);
      a2c = mfma16h(af, w2f[kk], a2c);
    }
    if (lr < 8) {
      const float b2v = b2[lr];
      #pragma unroll
      for (int q = 0; q < 4; q++) {
        const int p = mb + tile * 16 + lg * 4 + q;
        const int m0 = posPair[(bi * 640 + p) * 2];
        const int m1 = posPair[(bi * 640 + p) * 2 + 1];
        const float val = a2c[q] + b2v;
        if (m0 >= 0) out[(size_t)m0 * 8 + lr] = val;
        if (m1 >= 0) out[(size_t)m1 * 8 + lr] = val;
      }
    }
  }
}

extern "C" void kernel_launch(void* const* d_in, const int* in_sizes, int n_in,
                              void* d_out, int out_size, void* d_ws, size_t ws_size,
                              hipStream_t stream) {
  const float* node_feats = (const float*)d_in[0];
  const float* q_feats    = (const float*)d_in[1];
  const int*   indexes    = (const int*)d_in[2];
  const float* v_obj = (const float*)d_in[3];
  const float* g_obj = (const float*)d_in[4];
  const float* b_obj = (const float*)d_in[5];
  const float* v_q   = (const float*)d_in[6];
  const float* g_q   = (const float*)d_in[7];
  const float* b_q   = (const float*)d_in[8];
  const float* v_l1  = (const float*)d_in[9];
  const float* g_l1  = (const float*)d_in[10];
  const float* b_l1  = (const float*)d_in[11];
  const float* v_l2  = (const float*)d_in[12];
  const float* g_l2  = (const float*)d_in[13];
  const float* b_l2  = (const float*)d_in[14];
  float* out = (float*)d_out;

  char* ws = (char*)d_ws;
  u16*   Wobjh   = (u16*)(ws + 0);               //  2,097,152
  u16*   Wqh     = (u16*)(ws + 2097152);         //  1,048,576
  u16*   W1f     = (u16*)(ws + 3145728);         //    262,144 (16x256x32 fp16, swz)
  u16*   W2p     = (u16*)(ws + 3407872);         //      8,192
  u16*   qp_h    = (u16*)(ws + 3416064);         //    131,072 (128x512 fp16)
  u16*   A2h     = (u16*)(ws + 3547136);         //  4,718,592 (nf fp16)
  int*   posPair = (int*)(ws + 8265728);         //    655,360 (128x640x2)
  int*   ij_tab  = (int*)(ws + 8921088);         //      2,560 (640)
  float* part    = (float*)(ws + 8923648);       //  2,097,152

  hipMemsetAsync(posPair, 0xFF, 655360, stream);

  wn_scatter<<<dim3(960), dim3(256), 0, stream>>>(v_obj, g_obj, v_q, g_q, v_l1, g_l1,
                                                  v_l2, g_l2, Wobjh, Wqh, W1f, W2p,
                                                  indexes, posPair, ij_tab);

  // qp = q @ Wq^T + b_q: split-K(8), fused fp32-A
  gemm_f2<0><<<dim3(1, 8, 8), dim3(256), 0, stream>>>(q_feats, Wqh, 1024, 2,
                                                      nullptr, part, nullptr);
  qp_reduce<<<dim3(64), dim3(256), 0, stream>>>(part, b_q, qp_h);

  // nf = node @ Wobj^T + b_obj (fp16 out), fused fp32-A
  gemm_f2<1><<<dim3(36, 8), dim3(256), 0, stream>>>(node_feats, Wobjh, 2048, 32,
                                                    b_obj, nullptr, A2h);

  edge_v11<<<dim3(5, 128), dim3(256), EDGE_SMEM, stream>>>(A2h, qp_h, W1f, b_l1,
                                                           W2p, b_l2, posPair, ij_tab, out);
}

// Round 17
// 100.163 us; speedup vs baseline: 1.1896x; 1.0180x over previous
//
#include <hip/hip_runtime.h>
#include <hip/hip_fp16.h>

typedef __attribute__((ext_vector_type(8))) _Float16 half8;
typedef __attribute__((ext_vector_type(2))) __fp16 fp16x2;
typedef __attribute__((ext_vector_type(4))) float f32x4;
typedef unsigned short u16;
typedef unsigned int u32;

__device__ __forceinline__ u16 f2h(float f) {
  union { _Float16 h; u16 u; } cv; cv.h = (_Float16)f; return cv.u;
}

__device__ __forceinline__ u32 pkrtz(float a, float b) {
  union { fp16x2 h; u32 u; } cv;
  cv.h = __builtin_amdgcn_cvt_pkrtz(a, b);
  return cv.u;
}

__device__ __forceinline__ f32x4 mfma16h(half8 a, half8 b, f32x4 c) {
  return __builtin_amdgcn_mfma_f32_16x16x32_f16(a, b, c, 0, 0, 0);
}

__device__ __forceinline__ void gload_lds16(const void* g, void* l) {
  __builtin_amdgcn_global_load_lds(
      (const __attribute__((address_space(1))) void*)g,
      (__attribute__((address_space(3))) void*)l, 16, 0, 0);
}

__device__ __forceinline__ half8 ldh8(const char* p) {
  union { half8 h; int4 v; } r; r.v = *(const int4*)p; return r.h;
}

// 8-wide fp16 product via v_pk_mul_f16
__device__ __forceinline__ uint4 pkmul4(uint4 x, uint4 y) {
  union U { uint4 v; __half2 h[4]; };
  U X, Y, E; X.v = x; Y.v = y;
  #pragma unroll
  for (int i = 0; i < 4; i++) E.h[i] = __hmul2(X.h[i], Y.h[i]);
  return E.v;
}
__device__ __forceinline__ half8 as_h8(uint4 v) {
  union { uint4 v; half8 h; } r; r.v = v; return r.h;
}

// ---- one row of weight-norm (fp16 out), wave-cooperative ----
__device__ __forceinline__ void wn_row(const float* __restrict__ v,
                                       const float* __restrict__ g,
                                       int K, int Nreal, u16* __restrict__ outW,
                                       int row, int l) {
  if (row >= Nreal) {
    for (int k = l; k < K; k += 64) outW[row * K + k] = 0;
    return;
  }
  const float* vr = v + (size_t)row * K;
  float ss = 0.f;
  for (int k = l * 4; k < K; k += 256) {
    f32x4 x = *(const f32x4*)(vr + k);
    ss += x.x * x.x + x.y * x.y + x.z * x.z + x.w * x.w;
  }
  #pragma unroll
  for (int m = 32; m >= 1; m >>= 1) ss += __shfl_xor(ss, m, 64);
  const float scale = g[row] / sqrtf(ss);
  for (int k = l; k < K; k += 64) outW[row * K + k] = f2h(vr[k] * scale);
}

// ---- merged prep: weight-norm (blocks 0..323) + pos scatter / ij_tab (324..959) ----
// W1f layout: [kc(16)][row(256)][32] fp16, quad q stored at q ^ ((row>>1)&3).
// posPair stride 672 per batch; ij_tab has 672 entries (pads -> 35*36+35).
__global__ __launch_bounds__(256) void wn_scatter(
    const float* __restrict__ v_obj, const float* __restrict__ g_obj,
    const float* __restrict__ v_q,   const float* __restrict__ g_q,
    const float* __restrict__ v_l1,  const float* __restrict__ g_l1,
    const float* __restrict__ v_l2,  const float* __restrict__ g_l2,
    u16* __restrict__ Wobjh, u16* __restrict__ Wqh,
    u16* __restrict__ W1f,   u16* __restrict__ W2p,
    const int* __restrict__ indexes, int* __restrict__ posPair,
    int* __restrict__ ij_tab) {
  const int b = blockIdx.x;
  const int sub = threadIdx.x >> 6, l = threadIdx.x & 63;
  if (b < 128) {
    wn_row(v_obj, g_obj, 2048, 512, Wobjh, b * 4 + sub, l);
  } else if (b < 256) {
    wn_row(v_q, g_q, 1024, 512, Wqh, (b - 128) * 4 + sub, l);
  } else if (b < 320) {
    const int row = (b - 256) * 4 + sub;
    const float* vr = v_l1 + (size_t)row * 512;
    float ss = 0.f;
    for (int k = l * 4; k < 512; k += 256) {
      f32x4 x = *(const f32x4*)(vr + k);
      ss += x.x * x.x + x.y * x.y + x.z * x.z + x.w * x.w;
    }
    #pragma unroll
    for (int m = 32; m >= 1; m >>= 1) ss += __shfl_xor(ss, m, 64);
    const float scale = g_l1[row] / sqrtf(ss);
    const int swz = (row >> 1) & 3;
    for (int c = l; c < 512; c += 64) {
      const int kc = c >> 5, col = c & 31, q = col >> 3, e = col & 7;
      W1f[kc * 8192 + row * 32 + ((q ^ swz) << 3) + e] = f2h(vr[c] * scale);
    }
  } else if (b < 324) {
    wn_row(v_l2, g_l2, 256, 8, W2p, (b - 320) * 4 + sub, l);
  } else {
    const int m = (b - 324) * 256 + threadIdx.x;
    if (m < 161280) {
      const int idx = indexes[m];
      const int bi = idx / 1296;
      const int rem = idx - bi * 1296;
      const int i = rem / 36, j = rem - i * 36;
      const int i2 = (i < j) ? i : j, j2 = (i < j) ? j : i;
      const int p = i2 * (71 - i2) / 2 + (j2 - i2 - 1);
      posPair[(bi * 672 + p) * 2 + ((i < j) ? 0 : 1)] = m;
    } else {
      const int u = m - 161280;
      if (u < 1296) {
        const int i = u / 36, j = u - i * 36;
        if (i < j) ij_tab[i * (71 - i) / 2 + (j - i - 1)] = u;
      } else if (u < 1338) {
        ij_tab[630 + (u - 1296)] = 35 * 36 + 35;
      }
    }
  }
}

// ---- bulk fp32 -> fp16 convert: node (9437184) then q (131072), one launch ----
__global__ void cvt_all(const float* __restrict__ node, u16* __restrict__ node_h,
                        const float* __restrict__ qf, u16* __restrict__ q_h) {
  const int i = (blockIdx.x * 256 + threadIdx.x) * 8;
  const float* in; u16* out; int off;
  if (i < 9437184) { in = node; out = node_h; off = i; }
  else             { in = qf;   out = q_h;    off = i - 9437184; }
  f32x4 a = *(const f32x4*)(in + off);
  f32x4 b = *(const f32x4*)(in + off + 4);
  uint4 r;
  r.x = pkrtz(a.x, a.y); r.y = pkrtz(a.z, a.w);
  r.z = pkrtz(b.x, b.y); r.w = pkrtz(b.z, b.w);
  *(uint4*)(out + off) = r;
}

// ================= LDS-staged stage-1 GEMM, fp16, 128x64 tile (R12 proven) =================
template <int MODE>
__global__ __launch_bounds__(256, 3) void gemm_lds(
    const u16* __restrict__ Ab, const u16* __restrict__ Wb,
    int K, int nstep, const float* __restrict__ bias,
    float* __restrict__ fout, u16* __restrict__ o_a2) {
  __shared__ char smem[2][24576];
  const int t = threadIdx.x, l = t & 63, w = t >> 6;
  const int lr = l & 15, lg = l >> 4;
  const int wm = w & 1, wn2 = w >> 1;
  const int bm = blockIdx.x * 128, bn = blockIdx.y * 64;
  const int kbase = (MODE == 0) ? blockIdx.z * 128 : 0;
  const int ldb = K * 2;

  const char* Abase = (const char*)(Ab + (size_t)bm * K + kbase);
  const char* Bbase = (const char*)(Wb + (size_t)bn * K + kbase);

  auto stage = [&](int buf, int ks) {
    const char* asrc = Abase + ks * 128;
    const char* bsrc = Bbase + ks * 128;
    #pragma unroll
    for (int it = 0; it < 4; it++) {
      const int c = it * 256 + w * 64 + l;
      const int row = c >> 3;
      const int cb = ((c & 7) * 16) ^ ((row & 7) << 4);
      gload_lds16(asrc + (size_t)row * ldb + cb, &smem[buf][(it * 256 + w * 64) * 16]);
    }
    #pragma unroll
    for (int it = 0; it < 2; it++) {
      const int c = it * 256 + w * 64 + l;
      const int row = c >> 3;
      const int cb = ((c & 7) * 16) ^ ((row & 7) << 4);
      gload_lds16(bsrc + (size_t)row * ldb + cb,
                  &smem[buf][16384 + (it * 256 + w * 64) * 16]);
    }
  };

  stage(0, 0);
  asm volatile("s_waitcnt vmcnt(0)" ::: "memory");
  __builtin_amdgcn_s_barrier();

  f32x4 acc[4][2] = {};
  for (int ks = 0; ks < nstep; ks++) {
    const int cur = ks & 1;
    if (ks + 1 < nstep) stage(cur ^ 1, ks + 1);
    const char* As = smem[cur];
    const char* Bs = smem[cur] + 16384;
    #pragma unroll
    for (int kk = 0; kk < 2; kk++) {
      half8 af[4], bf[2];
      #pragma unroll
      for (int m = 0; m < 4; m++) {
        const int r = wm * 64 + m * 16 + lr;
        af[m] = ldh8(As + r * 128 + ((kk * 64 + lg * 16) ^ ((lr & 7) << 4)));
      }
      #pragma unroll
      for (int n = 0; n < 2; n++) {
        const int r = wn2 * 32 + n * 16 + lr;
        bf[n] = ldh8(Bs + r * 128 + ((kk * 64 + lg * 16) ^ ((lr & 7) << 4)));
      }
      #pragma unroll
      for (int m = 0; m < 4; m++)
        #pragma unroll
        for (int n = 0; n < 2; n++)
          acc[m][n] = mfma16h(af[m], bf[n], acc[m][n]);
    }
    asm volatile("s_waitcnt vmcnt(0)" ::: "memory");
    __builtin_amdgcn_s_barrier();
  }

  #pragma unroll
  for (int n = 0; n < 2; n++) {
    const int c = bn + wn2 * 32 + n * 16 + lr;
    const float bv = (MODE == 1) ? bias[c] : 0.f;
    #pragma unroll
    for (int m = 0; m < 4; m++) {
      #pragma unroll
      for (int q = 0; q < 4; q++) {
        const int r = bm + wm * 64 + m * 16 + lg * 4 + q;
        const float val = acc[m][n][q];
        if (MODE == 0) {
          fout[((size_t)blockIdx.z * 128 + r) * 512 + c] = val;
        } else {
          o_a2[(size_t)r * 512 + c] = f2h(val + bv);
        }
      }
    }
  }
}

// ---- split-K reduce for qp -> fp16 ----
__global__ void qp_reduce(const float* __restrict__ part, const float* __restrict__ bq,
                          u16* __restrict__ qp_h) {
  const int i = (blockIdx.x * 256 + threadIdx.x) * 4;
  f32x4 s = *(const f32x4*)(part + i);
  #pragma unroll
  for (int k = 1; k < 8; k++) {
    f32x4 v = *(const f32x4*)(part + (size_t)k * 65536 + i);
    s.x += v.x; s.y += v.y; s.z += v.z; s.w += v.w;
  }
  const int c = i & 511;
  uint2 r;
  r.x = pkrtz(s.x + bq[c], s.y + bq[c + 1]);
  r.y = pkrtz(s.z + bq[c + 2], s.w + bq[c + 3]);
  *(uint2*)(qp_h + i) = r;
}

// ================= fused edge kernel v13: 3 blocks/CU =================
// M=96 pair-rows/block, grid (7,128) = 896 blocks (pair space padded to 672).
// nf table: [36][1024B] with T2 XOR swizzle (chunk c of row r stored at
// (c*16)^((r&7)<<4); staged via pre-swizzled per-lane GLOBAL src, linear LDS
// dest — rule #21). qp [1024B] linear. W1 SINGLE buffer 16KB, v4-proven
// reg-staging (load kc+1 -> regs || compute kc; barrier; regs -> LDS; barrier).
// LDS = 36*1024 + 1024 + 16384 = 54,272 B -> 3 blocks/CU (12 waves).
// Epilogue h-tile [96][528B] = 50,688 aliases tables+W1.
#define OFF_QP 36864
#define OFF_W1 37888
#define EDGE_SMEM 54272

__global__ __launch_bounds__(256, 3) void edge_v13(
    const u16* __restrict__ NFg, const u16* __restrict__ QPg,
    const u16* __restrict__ W1f, const float* __restrict__ b1,
    const u16* __restrict__ W2p, const float* __restrict__ b2,
    const int* __restrict__ posPair, const int* __restrict__ ij_tab,
    float* __restrict__ out) {
  extern __shared__ char smem[];
  const int t = threadIdx.x, l = t & 63, w = t >> 6;
  const int lr = l & 15, lg = l >> 4;
  const int wm = w & 1, wn = w >> 1;
  const int bi = blockIdx.y;
  const int mb = blockIdx.x * 96;

  // ---- prologue: nf rows 0..35 (swizzled src, linear dest) + qp + W1(0) ----
  #pragma unroll
  for (int it = 0; it < 10; it++) {
    const int row = it * 4 + w;            // wave-uniform
    if (row < 36) {
      // lane l: global chunk l ^ ((row&7)<<1) in 8-elem units -> elem offset
      gload_lds16(NFg + (size_t)(bi * 36 + row) * 512 + ((l * 8) ^ ((row & 7) << 3)),
                  smem + row * 1024);
    } else if (row == 36) {
      gload_lds16(QPg + (size_t)bi * 512 + l * 8, smem + OFF_QP);
    }
  }
  #pragma unroll
  for (int it = 0; it < 4; it++) {
    gload_lds16(W1f + (size_t)(it * 256 + w * 64 + l) * 8,
                smem + OFF_W1 + (it * 256 + w * 64) * 16);
  }

  // ---- per-thread A-gen offsets for the 3 m-tiles (pair -> i,j via ij_tab) ----
  int xoff[3], yoff[3], xsw[3], ysw[3];
  #pragma unroll
  for (int m = 0; m < 3; m++) {
    const int p = mb + wm * 48 + m * 16 + lr;   // <= 671
    const int pij = ij_tab[p];
    const int ii = pij / 36;
    const int jj = pij - ii * 36;
    xoff[m] = ii * 1024; xsw[m] = (ii & 7) << 4;
    yoff[m] = jj * 1024; ysw[m] = (jj & 7) << 4;
  }
  const int qoff = OFF_QP + lg * 16;
  const int bswz = ((lr >> 1) & 3) << 4;

  asm volatile("s_waitcnt vmcnt(0)" ::: "memory");
  __builtin_amdgcn_s_barrier();             // tables + W1(0) ready

  f32x4 acc[3][8] = {};

  for (int kc = 0; kc < 16; kc++) {
    const bool more = (kc < 15);
    int4 s0, s1, s2, s3;
    if (more) {                             // W1(kc+1) global -> regs (T14)
      const u16* ws1 = W1f + (size_t)(kc + 1) * 8192;
      s0 = *(const int4*)(ws1 + (t) * 8);
      s1 = *(const int4*)(ws1 + (t + 256) * 8);
      s2 = *(const int4*)(ws1 + (t + 512) * 8);
      s3 = *(const int4*)(ws1 + (t + 768) * 8);
    }
    // compute kc
    {
      const int kb = kc * 64;
      const uint4 qv = *(const uint4*)(smem + qoff + kb);
      half8 bf[8];
      #pragma unroll
      for (int n = 0; n < 8; n++)
        bf[n] = ldh8(smem + OFF_W1 + (wn * 128 + n * 16 + lr) * 64 + ((lg * 16) ^ bswz));
      #pragma unroll
      for (int m = 0; m < 3; m++) {
        const int ko = lg * 16 + kb;
        uint4 x = *(const uint4*)(smem + xoff[m] + (ko ^ xsw[m]));
        uint4 y = *(const uint4*)(smem + yoff[m] + (ko ^ ysw[m]));
        half8 af = as_h8(pkmul4(pkmul4(x, y), qv));
        #pragma unroll
        for (int n = 0; n < 8; n++)
          acc[m][n] = mfma16h(af, bf[n], acc[m][n]);
      }
    }
    __syncthreads();                        // all waves done reading W1[kc]
    if (more) {
      *(int4*)(smem + OFF_W1 + (t) * 16) = s0;
      *(int4*)(smem + OFF_W1 + (t + 256) * 16) = s1;
      *(int4*)(smem + OFF_W1 + (t + 512) * 16) = s2;
      *(int4*)(smem + OFF_W1 + (t + 768) * 16) = s3;
    }
    __syncthreads();                        // W1(kc+1) visible
  }

  // ---- epilogue: bias+relu -> fp16 h tile [96][528B] (aliases tables/W1) ----
  #pragma unroll
  for (int m = 0; m < 3; m++) {
    #pragma unroll
    for (int n = 0; n < 8; n++) {
      const int c = wn * 128 + n * 16 + lr;
      const float bv = b1[c];
      #pragma unroll
      for (int qq = 0; qq < 2; qq++) {
        const float v0 = fmaxf(acc[m][n][2 * qq] + bv, 0.f);
        const float v1 = fmaxf(acc[m][n][2 * qq + 1] + bv, 0.f);
        const u32 pk = pkrtz(v0, v1);
        const int r = wm * 48 + m * 16 + lg * 4 + 2 * qq;
        *(u16*)(smem + r * 528 + c * 2) = (u16)pk;
        *(u16*)(smem + (r + 1) * 528 + c * 2) = (u16)(pk >> 16);
      }
    }
  }
  __syncthreads();

  // ---- GEMM2: out = h @ W2p^T + b2, K=256; 6 row-tiles over 4 waves ----
  half8 w2f[8];
  #pragma unroll
  for (int kk = 0; kk < 8; kk++)
    w2f[kk] = ldh8((const char*)(W2p + lr * 256 + kk * 32 + lg * 8));

  #pragma unroll
  for (int tt = 0; tt < 2; tt++) {
    const int tile = tt * 4 + w;
    if (tile < 6) {
      f32x4 a2c = {0.f, 0.f, 0.f, 0.f};
      #pragma unroll
      for (int kk = 0; kk < 8; kk++) {
        half8 af = ldh8(smem + (tile * 16 + lr) * 528 + kk * 64 + lg * 16);
        a2c = mfma16h(af, w2f[kk], a2c);
      }
      if (lr < 8) {
        const float b2v = b2[lr];
        #pragma unroll
        for (int q = 0; q < 4; q++) {
          const int p = mb + tile * 16 + lg * 4 + q;
          const int m0 = posPair[(bi * 672 + p) * 2];
          const int m1 = posPair[(bi * 672 + p) * 2 + 1];
          const float val = a2c[q] + b2v;
          if (m0 >= 0) out[(size_t)m0 * 8 + lr] = val;
          if (m1 >= 0) out[(size_t)m1 * 8 + lr] = val;
        }
      }
    }
  }
}

extern "C" void kernel_launch(void* const* d_in, const int* in_sizes, int n_in,
                              void* d_out, int out_size, void* d_ws, size_t ws_size,
                              hipStream_t stream) {
  const float* node_feats = (const float*)d_in[0];
  const float* q_feats    = (const float*)d_in[1];
  const int*   indexes    = (const int*)d_in[2];
  const float* v_obj = (const float*)d_in[3];
  const float* g_obj = (const float*)d_in[4];
  const float* b_obj = (const float*)d_in[5];
  const float* v_q   = (const float*)d_in[6];
  const float* g_q   = (const float*)d_in[7];
  const float* b_q   = (const float*)d_in[8];
  const float* v_l1  = (const float*)d_in[9];
  const float* g_l1  = (const float*)d_in[10];
  const float* b_l1  = (const float*)d_in[11];
  const float* v_l2  = (const float*)d_in[12];
  const float* g_l2  = (const float*)d_in[13];
  const float* b_l2  = (const float*)d_in[14];
  float* out = (float*)d_out;

  char* ws = (char*)d_ws;
  u16*   node_h  = (u16*)(ws + 0);               // 18,874,368
  u16*   q_h     = (u16*)(ws + 18874368);        //    262,144
  u16*   Wobjh   = (u16*)(ws + 19136512);        //  2,097,152
  u16*   Wqh     = (u16*)(ws + 21233664);        //  1,048,576
  u16*   W1f     = (u16*)(ws + 22282240);        //    262,144 (16x256x32 fp16, swz)
  u16*   W2p     = (u16*)(ws + 22544384);        //      8,192
  u16*   qp_h    = (u16*)(ws + 22552576);        //    131,072 (128x512 fp16)
  u16*   A2h     = (u16*)(ws + 22683648);        //  4,718,592 (nf fp16)
  int*   posPair = (int*)(ws + 27402240);        //    688,128 (128x672x2)
  int*   ij_tab  = (int*)(ws + 28090368);        //      2,688 (672)
  float* part    = (float*)(ws + 28093056);      //  2,097,152

  hipMemsetAsync(posPair, 0xFF, 688128, stream);

  wn_scatter<<<dim3(960), dim3(256), 0, stream>>>(v_obj, g_obj, v_q, g_q, v_l1, g_l1,
                                                  v_l2, g_l2, Wobjh, Wqh, W1f, W2p,
                                                  indexes, posPair, ij_tab);

  cvt_all<<<dim3(4672), dim3(256), 0, stream>>>(node_feats, node_h, q_feats, q_h);

  gemm_lds<0><<<dim3(1, 8, 8), dim3(256), 0, stream>>>(q_h, Wqh, 1024, 2, nullptr,
                                                       part, nullptr);
  qp_reduce<<<dim3(64), dim3(256), 0, stream>>>(part, b_q, qp_h);

  gemm_lds<1><<<dim3(36, 8), dim3(256), 0, stream>>>(node_h, Wobjh, 2048, 32, b_obj,
                                                     nullptr, A2h);

  edge_v13<<<dim3(7, 128), dim3(256), EDGE_SMEM, stream>>>(A2h, qp_h, W1f, b_l1,
                                                           W2p, b_l2, posPair, ij_tab, out);
}

// Round 18
// 94.343 us; speedup vs baseline: 1.2630x; 1.0617x over previous
//
#include <hip/hip_runtime.h>
#include <hip/hip_fp16.h>

typedef __attribute__((ext_vector_type(8))) _Float16 half8;
typedef __attribute__((ext_vector_type(2))) __fp16 fp16x2;
typedef __attribute__((ext_vector_type(4))) float f32x4;
typedef unsigned short u16;
typedef unsigned int u32;

__device__ __forceinline__ u16 f2h(float f) {
  union { _Float16 h; u16 u; } cv; cv.h = (_Float16)f; return cv.u;
}

__device__ __forceinline__ u32 pkrtz(float a, float b) {
  union { fp16x2 h; u32 u; } cv;
  cv.h = __builtin_amdgcn_cvt_pkrtz(a, b);
  return cv.u;
}

__device__ __forceinline__ f32x4 mfma16h(half8 a, half8 b, f32x4 c) {
  return __builtin_amdgcn_mfma_f32_16x16x32_f16(a, b, c, 0, 0, 0);
}

__device__ __forceinline__ void gload_lds16(const void* g, void* l) {
  __builtin_amdgcn_global_load_lds(
      (const __attribute__((address_space(1))) void*)g,
      (__attribute__((address_space(3))) void*)l, 16, 0, 0);
}

__device__ __forceinline__ half8 ldh8(const char* p) {
  union { half8 h; int4 v; } r; r.v = *(const int4*)p; return r.h;
}

// 8-wide fp16 product via v_pk_mul_f16
__device__ __forceinline__ uint4 pkmul4(uint4 x, uint4 y) {
  union U { uint4 v; __half2 h[4]; };
  U X, Y, E; X.v = x; Y.v = y;
  #pragma unroll
  for (int i = 0; i < 4; i++) E.h[i] = __hmul2(X.h[i], Y.h[i]);
  return E.v;
}
__device__ __forceinline__ half8 as_h8(uint4 v) {
  union { uint4 v; half8 h; } r; r.v = v; return r.h;
}

// ---- one row of weight-norm (fp16 out), wave-cooperative ----
__device__ __forceinline__ void wn_row(const float* __restrict__ v,
                                       const float* __restrict__ g,
                                       int K, int Nreal, u16* __restrict__ outW,
                                       int row, int l) {
  if (row >= Nreal) {
    for (int k = l; k < K; k += 64) outW[row * K + k] = 0;
    return;
  }
  const float* vr = v + (size_t)row * K;
  float ss = 0.f;
  for (int k = l * 4; k < K; k += 256) {
    f32x4 x = *(const f32x4*)(vr + k);
    ss += x.x * x.x + x.y * x.y + x.z * x.z + x.w * x.w;
  }
  #pragma unroll
  for (int m = 32; m >= 1; m >>= 1) ss += __shfl_xor(ss, m, 64);
  const float scale = g[row] / sqrtf(ss);
  for (int k = l; k < K; k += 64) outW[row * K + k] = f2h(vr[k] * scale);
}

// ================= merged prep: cvt (0..4671) + weight-norm (4672..4995) +
// pos scatter / ij_tab (4996..5631), one launch =================
// W1f layout: [kc(16)][row(256)][32] fp16, quad q stored at q ^ ((row>>1)&3).
// posPair stride 640/batch; ij_tab 640 entries (pads -> 35*36+35).
__global__ __launch_bounds__(256) void prep(
    const float* __restrict__ node, u16* __restrict__ node_h,
    const float* __restrict__ qf, u16* __restrict__ q_h,
    const float* __restrict__ v_obj, const float* __restrict__ g_obj,
    const float* __restrict__ v_q,   const float* __restrict__ g_q,
    const float* __restrict__ v_l1,  const float* __restrict__ g_l1,
    const float* __restrict__ v_l2,  const float* __restrict__ g_l2,
    u16* __restrict__ Wobjh, u16* __restrict__ Wqh,
    u16* __restrict__ W1f,   u16* __restrict__ W2p,
    const int* __restrict__ indexes, int* __restrict__ posPair,
    int* __restrict__ ij_tab) {
  const int b = blockIdx.x;
  if (b < 4672) {
    const int i = (b * 256 + threadIdx.x) * 8;
    const float* in; u16* out; int off;
    if (i < 9437184) { in = node; out = node_h; off = i; }
    else             { in = qf;   out = q_h;    off = i - 9437184; }
    f32x4 a = *(const f32x4*)(in + off);
    f32x4 c = *(const f32x4*)(in + off + 4);
    uint4 r;
    r.x = pkrtz(a.x, a.y); r.y = pkrtz(a.z, a.w);
    r.z = pkrtz(c.x, c.y); r.w = pkrtz(c.z, c.w);
    *(uint4*)(out + off) = r;
    return;
  }
  const int sub = threadIdx.x >> 6, l = threadIdx.x & 63;
  const int b2 = b - 4672;
  if (b2 < 128) {
    wn_row(v_obj, g_obj, 2048, 512, Wobjh, b2 * 4 + sub, l);
  } else if (b2 < 256) {
    wn_row(v_q, g_q, 1024, 512, Wqh, (b2 - 128) * 4 + sub, l);
  } else if (b2 < 320) {
    const int row = (b2 - 256) * 4 + sub;
    const float* vr = v_l1 + (size_t)row * 512;
    float ss = 0.f;
    for (int k = l * 4; k < 512; k += 256) {
      f32x4 x = *(const f32x4*)(vr + k);
      ss += x.x * x.x + x.y * x.y + x.z * x.z + x.w * x.w;
    }
    #pragma unroll
    for (int m = 32; m >= 1; m >>= 1) ss += __shfl_xor(ss, m, 64);
    const float scale = g_l1[row] / sqrtf(ss);
    const int swz = (row >> 1) & 3;
    for (int c = l; c < 512; c += 64) {
      const int kc = c >> 5, col = c & 31, q = col >> 3, e = col & 7;
      W1f[kc * 8192 + row * 32 + ((q ^ swz) << 3) + e] = f2h(vr[c] * scale);
    }
  } else if (b2 < 324) {
    wn_row(v_l2, g_l2, 256, 8, W2p, (b2 - 320) * 4 + sub, l);
  } else {
    const int m = (b2 - 324) * 256 + threadIdx.x;
    if (m < 161280) {
      const int idx = indexes[m];
      const int bi = idx / 1296;
      const int rem = idx - bi * 1296;
      const int i = rem / 36, j = rem - i * 36;
      const int i2 = (i < j) ? i : j, j2 = (i < j) ? j : i;
      const int p = i2 * (71 - i2) / 2 + (j2 - i2 - 1);
      posPair[(bi * 640 + p) * 2 + ((i < j) ? 0 : 1)] = m;
    } else {
      const int u = m - 161280;
      if (u < 1296) {
        const int i = u / 36, j = u - i * 36;
        if (i < j) ij_tab[i * (71 - i) / 2 + (j - i - 1)] = u;
      } else if (u < 1306) {
        ij_tab[630 + (u - 1296)] = 35 * 36 + 35;
      }
    }
  }
}

// ================= merged stage-1 GEMM (nf: bx<36, qp: bx==36) =================
// 128x64 tile, BK=64, 4 waves, gload_lds XOR-swizzled staging (R12-proven).
// nf: A=node_h K=2048 (32 steps) -> A2h = f16(C + b_obj).
// qp: A=q_h K=1024 (16 steps), bm=0 -> qp_h = f16(C + b_q).
__global__ __launch_bounds__(256, 3) void gemm_merged(
    const u16* __restrict__ node_h, const u16* __restrict__ Wobjh,
    const float* __restrict__ b_obj, u16* __restrict__ A2h,
    const u16* __restrict__ q_h, const u16* __restrict__ Wqh,
    const float* __restrict__ b_q, u16* __restrict__ qp_h) {
  __shared__ char smem[2][24576];
  const int t = threadIdx.x, l = t & 63, w = t >> 6;
  const int lr = l & 15, lg = l >> 4;
  const int wm = w & 1, wn2 = w >> 1;

  const bool isq = (blockIdx.x == 36);
  const u16* Ab = isq ? q_h : node_h;
  const u16* Wb = isq ? Wqh : Wobjh;
  const float* bias = isq ? b_q : b_obj;
  u16* outp = isq ? qp_h : A2h;
  const int K = isq ? 1024 : 2048;
  const int nstep = isq ? 16 : 32;
  const int bm = isq ? 0 : blockIdx.x * 128;
  const int bn = blockIdx.y * 64;
  const int ldb = K * 2;

  const char* Abase = (const char*)(Ab + (size_t)bm * K);
  const char* Bbase = (const char*)(Wb + (size_t)bn * K);

  auto stage = [&](int buf, int ks) {
    const char* asrc = Abase + ks * 128;
    const char* bsrc = Bbase + ks * 128;
    #pragma unroll
    for (int it = 0; it < 4; it++) {
      const int c = it * 256 + w * 64 + l;
      const int row = c >> 3;
      const int cb = ((c & 7) * 16) ^ ((row & 7) << 4);
      gload_lds16(asrc + (size_t)row * ldb + cb, &smem[buf][(it * 256 + w * 64) * 16]);
    }
    #pragma unroll
    for (int it = 0; it < 2; it++) {
      const int c = it * 256 + w * 64 + l;
      const int row = c >> 3;
      const int cb = ((c & 7) * 16) ^ ((row & 7) << 4);
      gload_lds16(bsrc + (size_t)row * ldb + cb,
                  &smem[buf][16384 + (it * 256 + w * 64) * 16]);
    }
  };

  stage(0, 0);
  asm volatile("s_waitcnt vmcnt(0)" ::: "memory");
  __builtin_amdgcn_s_barrier();

  f32x4 acc[4][2] = {};
  for (int ks = 0; ks < nstep; ks++) {
    const int cur = ks & 1;
    if (ks + 1 < nstep) stage(cur ^ 1, ks + 1);
    const char* As = smem[cur];
    const char* Bs = smem[cur] + 16384;
    #pragma unroll
    for (int kk = 0; kk < 2; kk++) {
      half8 af[4], bf[2];
      #pragma unroll
      for (int m = 0; m < 4; m++) {
        const int r = wm * 64 + m * 16 + lr;
        af[m] = ldh8(As + r * 128 + ((kk * 64 + lg * 16) ^ ((lr & 7) << 4)));
      }
      #pragma unroll
      for (int n = 0; n < 2; n++) {
        const int r = wn2 * 32 + n * 16 + lr;
        bf[n] = ldh8(Bs + r * 128 + ((kk * 64 + lg * 16) ^ ((lr & 7) << 4)));
      }
      #pragma unroll
      for (int m = 0; m < 4; m++)
        #pragma unroll
        for (int n = 0; n < 2; n++)
          acc[m][n] = mfma16h(af[m], bf[n], acc[m][n]);
    }
    asm volatile("s_waitcnt vmcnt(0)" ::: "memory");
    __builtin_amdgcn_s_barrier();
  }

  #pragma unroll
  for (int n = 0; n < 2; n++) {
    const int c = bn + wn2 * 32 + n * 16 + lr;
    const float bv = bias[c];
    #pragma unroll
    for (int m = 0; m < 4; m++) {
      #pragma unroll
      for (int q = 0; q < 4; q++) {
        const int r = bm + wm * 64 + m * 16 + lg * 4 + q;
        outp[(size_t)r * 512 + c] = f2h(acc[m][n][q] + bv);
      }
    }
  }
}

// ================= fused edge kernel v11 (R12-proven, 45.7 us) =================
#define OFF_QP 37440
#define OFF_W1 38464
#define EDGE_SMEM 71232

__global__ __launch_bounds__(256, 2) void edge_v11(
    const u16* __restrict__ NFg, const u16* __restrict__ QPg,
    const u16* __restrict__ W1f, const float* __restrict__ b1,
    const u16* __restrict__ W2p, const float* __restrict__ b2,
    const int* __restrict__ posPair, const int* __restrict__ ij_tab,
    float* __restrict__ out) {
  extern __shared__ char smem[];
  const int t = threadIdx.x, l = t & 63, w = t >> 6;
  const int lr = l & 15, lg = l >> 4;
  const int wm = w & 1, wn = w >> 1;
  const int bi = blockIdx.y;
  const int mb = blockIdx.x * 128;

  #pragma unroll
  for (int it = 0; it < 10; it++) {
    const int row = it * 4 + w;
    if (row < 36) {
      gload_lds16(NFg + (size_t)(bi * 36 + row) * 512 + l * 8, smem + row * 1040);
    } else if (row == 36) {
      gload_lds16(QPg + (size_t)bi * 512 + l * 8, smem + OFF_QP);
    }
  }
  #pragma unroll
  for (int it = 0; it < 4; it++) {
    gload_lds16(W1f + (size_t)(it * 256 + w * 64 + l) * 8,
                smem + OFF_W1 + (it * 256 + w * 64) * 16);
  }

  int xoff[4], yoff[4];
  #pragma unroll
  for (int m = 0; m < 4; m++) {
    const int p = mb + wm * 64 + m * 16 + lr;
    const int pij = ij_tab[p];
    const int ii = pij / 36;
    const int jj = pij - ii * 36;
    xoff[m] = ii * 1040 + lg * 16;
    yoff[m] = jj * 1040 + lg * 16;
  }
  const int qoff = OFF_QP + lg * 16;
  const int bswz = ((lr >> 1) & 3) << 4;

  asm volatile("s_waitcnt vmcnt(0)" ::: "memory");
  __builtin_amdgcn_s_barrier();

  f32x4 acc[4][8] = {};
  int cur = 0;

  for (int kc = 0; kc < 16; kc++) {
    const int nxt = cur ^ 1;
    if (kc < 15) {
      #pragma unroll
      for (int it = 0; it < 4; it++) {
        gload_lds16(W1f + (size_t)(kc + 1) * 8192 + (size_t)(it * 256 + w * 64 + l) * 8,
                    smem + OFF_W1 + nxt * 16384 + (it * 256 + w * 64) * 16);
      }
    }
    {
      const char* w1c = smem + OFF_W1 + cur * 16384;
      const int kb = kc * 64;
      const uint4 qv = *(const uint4*)(smem + qoff + kb);
      half8 bf[8];
      #pragma unroll
      for (int n = 0; n < 8; n++)
        bf[n] = ldh8(w1c + (wn * 128 + n * 16 + lr) * 64 + ((lg * 16) ^ bswz));
      #pragma unroll
      for (int m = 0; m < 4; m++) {
        uint4 x = *(const uint4*)(smem + xoff[m] + kb);
        uint4 y = *(const uint4*)(smem + yoff[m] + kb);
        half8 af = as_h8(pkmul4(pkmul4(x, y), qv));
        #pragma unroll
        for (int n = 0; n < 8; n++)
          acc[m][n] = mfma16h(af, bf[n], acc[m][n]);
      }
    }
    asm volatile("s_waitcnt vmcnt(0)" ::: "memory");
    __builtin_amdgcn_s_barrier();
    cur = nxt;
  }

  #pragma unroll
  for (int m = 0; m < 4; m++) {
    #pragma unroll
    for (int n = 0; n < 8; n++) {
      const int c = wn * 128 + n * 16 + lr;
      const float bv = b1[c];
      #pragma unroll
      for (int qq = 0; qq < 2; qq++) {
        const float v0 = fmaxf(acc[m][n][2 * qq] + bv, 0.f);
        const float v1 = fmaxf(acc[m][n][2 * qq + 1] + bv, 0.f);
        const u32 pk = pkrtz(v0, v1);
        const int r = wm * 64 + m * 16 + lg * 4 + 2 * qq;
        *(u16*)(smem + r * 528 + c * 2) = (u16)pk;
        *(u16*)(smem + (r + 1) * 528 + c * 2) = (u16)(pk >> 16);
      }
    }
  }
  __syncthreads();

  half8 w2f[8];
  #pragma unroll
  for (int kk = 0; kk < 8; kk++)
    w2f[kk] = ldh8((const char*)(W2p + lr * 256 + kk * 32 + lg * 8));

  #pragma unroll
  for (int tt = 0; tt < 2; tt++) {
    const int tile = tt * 4 + w;
    f32x4 a2c = {0.f, 0.f, 0.f, 0.f};
    #pragma unroll
    for (int kk = 0; kk < 8; kk++) {
      half8 af = ldh8(smem + (tile * 16 + lr) * 528 + kk * 64 + lg * 16);
      a2c = mfma16h(af, w2f[kk], a2c);
    }
    if (lr < 8) {
      const float b2v = b2[lr];
      #pragma unroll
      for (int q = 0; q < 4; q++) {
        const int p = mb + tile * 16 + lg * 4 + q;
        const int m0 = posPair[(bi * 640 + p) * 2];
        const int m1 = posPair[(bi * 640 + p) * 2 + 1];
        const float val = a2c[q] + b2v;
        if (m0 >= 0) out[(size_t)m0 * 8 + lr] = val;
        if (m1 >= 0) out[(size_t)m1 * 8 + lr] = val;
      }
    }
  }
}

extern "C" void kernel_launch(void* const* d_in, const int* in_sizes, int n_in,
                              void* d_out, int out_size, void* d_ws, size_t ws_size,
                              hipStream_t stream) {
  const float* node_feats = (const float*)d_in[0];
  const float* q_feats    = (const float*)d_in[1];
  const int*   indexes    = (const int*)d_in[2];
  const float* v_obj = (const float*)d_in[3];
  const float* g_obj = (const float*)d_in[4];
  const float* b_obj = (const float*)d_in[5];
  const float* v_q   = (const float*)d_in[6];
  const float* g_q   = (const float*)d_in[7];
  const float* b_q   = (const float*)d_in[8];
  const float* v_l1  = (const float*)d_in[9];
  const float* g_l1  = (const float*)d_in[10];
  const float* b_l1  = (const float*)d_in[11];
  const float* v_l2  = (const float*)d_in[12];
  const float* g_l2  = (const float*)d_in[13];
  const float* b_l2  = (const float*)d_in[14];
  float* out = (float*)d_out;

  char* ws = (char*)d_ws;
  u16*   node_h  = (u16*)(ws + 0);               // 18,874,368
  u16*   q_h     = (u16*)(ws + 18874368);        //    262,144
  u16*   Wobjh   = (u16*)(ws + 19136512);        //  2,097,152
  u16*   Wqh     = (u16*)(ws + 21233664);        //  1,048,576
  u16*   W1f     = (u16*)(ws + 22282240);        //    262,144 (16x256x32 fp16, swz)
  u16*   W2p     = (u16*)(ws + 22544384);        //      8,192
  u16*   qp_h    = (u16*)(ws + 22552576);        //    131,072 (128x512 fp16)
  u16*   A2h     = (u16*)(ws + 22683648);        //  4,718,592 (nf fp16)
  int*   posPair = (int*)(ws + 27402240);        //    655,360 (128x640x2)
  int*   ij_tab  = (int*)(ws + 28057600);        //      2,560 (640)

  hipMemsetAsync(posPair, 0xFF, 655360, stream);

  prep<<<dim3(5632), dim3(256), 0, stream>>>(
      node_feats, node_h, q_feats, q_h,
      v_obj, g_obj, v_q, g_q, v_l1, g_l1, v_l2, g_l2,
      Wobjh, Wqh, W1f, W2p, indexes, posPair, ij_tab);

  gemm_merged<<<dim3(37, 8), dim3(256), 0, stream>>>(
      node_h, Wobjh, b_obj, A2h, q_h, Wqh, b_q, qp_h);

  edge_v11<<<dim3(5, 128), dim3(256), EDGE_SMEM, stream>>>(A2h, qp_h, W1f, b_l1,
                                                           W2p, b_l2, posPair, ij_tab, out);
}